// Round 3
// baseline (148.199 us; speedup 1.0000x reference)
//
#include <hip/hip_runtime.h>

#define BB 4
#define TT 1024
#define DD 128
#define LL 16
#define CC 64   // TT/LL
#define EPSV 1e-6f

// workspace offsets (floats)
#define OFF_QC   0
#define OFF_KH   (OFF_QC + BB*TT*DD)
#define OFF_V    (OFF_KH + BB*TT*DD)
#define OFF_CL   (OFF_V  + BB*TT*DD)
#define OFF_KS   (OFF_CL + BB*CC*DD)
#define OFF_Z0   (OFF_KS + BB*CC*DD)
#define OFF_U    (OFF_Z0 + BB*CC*DD)
#define OFF_S0   (OFF_U  + BB*CC*DD*DD)
#define OFF_WT   (OFF_S0 + BB*CC*DD*DD)
// total ~= 40.5 MB floats

// ---------------------------------------------------------------------------
// Kernel 0: transpose the 4 weight matrices into k-major float4 panels:
//   Wt[m][k4][j][kk] = W[m][j][4*k4+kk]
// so the GEMM reads a contiguous 2KB row per k-step. 8 blocks (m, j-half).
// ---------------------------------------------------------------------------
__global__ __launch_bounds__(256) void k_tw(
    const float* __restrict__ Wq, const float* __restrict__ Wk,
    const float* __restrict__ Wv, const float* __restrict__ Wa,
    float* __restrict__ wt)
{
    __shared__ float ls[64][133];
    const int m  = blockIdx.x >> 1;
    const int jh = blockIdx.x & 1;
    const float* W = (m==0)?Wq : (m==1)?Wk : (m==2)?Wv : Wa;
    const float* src = W + (size_t)jh*64*DD;
    const int tid = threadIdx.x;

    #pragma unroll
    for (int r=0;r<8;r++){
        int f = tid + r*256;            // f4 index over 64x128 half-tile
        int jl = f >> 5, c4 = f & 31;
        *(float4*)&ls[jl][c4*4] = ((const float4*)src)[f];
    }
    __syncthreads();
    float* dst = wt + (size_t)m*DD*DD;
    #pragma unroll
    for (int r=0;r<8;r++){
        int f = tid + r*256;            // output f4 within half
        int k4 = f >> 6, jl = f & 63;
        float4 v = *(const float4*)&ls[jl][k4*4];
        *(float4*)(dst + ((size_t)k4*DD + jh*64 + jl)*4) = v;
    }
}

// ---------------------------------------------------------------------------
// Kernel 1: per (b,chunk) block. q,k,v,a projections (coalesced Wt reads),
// activations, in-chunk gate cumprod, qc/kh/v/cL/Ksum, U = kb^T V.
// ---------------------------------------------------------------------------
__global__ __launch_bounds__(256) void k_proj(
    const float* __restrict__ x,
    const float* __restrict__ bq, const float* __restrict__ bk,
    const float* __restrict__ bv, const float* __restrict__ ba,
    const float* __restrict__ wt,
    float* __restrict__ ws)
{
    __shared__ float xs [LL][DD];
    __shared__ float cs [LL][DD];
    __shared__ float kbs[LL][DD];
    __shared__ float vsm[LL][DD];

    const int tid = threadIdx.x;
    const int bc  = blockIdx.x;        // b*CC + ch
    const int b   = bc / CC;
    const int ch  = bc % CC;
    const int t0  = ch * LL;

    // ---- load x tile [16][128] ----
    const float4* xg = (const float4*)(x + (size_t)(b*TT + t0)*DD);
    float4* xsv = (float4*)&xs[0][0];
    xsv[tid]       = xg[tid];
    xsv[tid + 256] = xg[tid + 256];
    __syncthreads();

    // ---- GEMM: wave m handles matrix m; thread owns 2 adjacent columns ----
    const int m  = tid >> 6;           // 0:q 1:k 2:v 3:a (wave-uniform)
    const int j2 = tid & 63;
    const int j0 = j2*2, j1 = j0+1;
    const float* bias = (m==0)?bq : (m==1)?bk : (m==2)?bv : ba;
    const float* wtm  = wt + (size_t)m*DD*DD;   // [32][128][4]

    float acc0[LL], acc1[LL];
    {
        float b0 = bias[j0], b1 = bias[j1];
        #pragma unroll
        for (int t=0;t<LL;t++){acc0[t]=b0;acc1[t]=b1;}
    }
    #pragma unroll 2
    for (int k4=0; k4<32; k4++){
        const float4* wr = (const float4*)(wtm + (size_t)k4*DD*4);
        float4 w0 = wr[j0];            // lanes read 2KB contiguous
        float4 w1 = wr[j1];
        #pragma unroll
        for (int t=0;t<LL;t++){
            float4 xv = *(const float4*)(&xs[t][k4*4]);
            acc0[t] = fmaf(w0.x,xv.x, fmaf(w0.y,xv.y, fmaf(w0.z,xv.z, fmaf(w0.w,xv.w, acc0[t]))));
            acc1[t] = fmaf(w1.x,xv.x, fmaf(w1.y,xv.y, fmaf(w1.z,xv.z, fmaf(w1.w,xv.w, acc1[t]))));
        }
    }

    // ---- a-wave: sigmoid + cumprod -> cs, cL ----
    if (m==3){
        float c0=1.f, c1=1.f;
        #pragma unroll
        for (int t=0;t<LL;t++){
            float g0 = 1.f/(1.f+__expf(-acc0[t]));
            float g1 = 1.f/(1.f+__expf(-acc1[t]));
            c0*=g0; c1*=g1;
            cs[t][j0]=c0; cs[t][j1]=c1;
        }
        float* cLg = ws + OFF_CL + (size_t)bc*DD;
        cLg[j0]=c0; cLg[j1]=c1;
    }
    __syncthreads();

    if (m==0){ // qc = relu(q)*c
        float* qcg = ws + OFF_QC + (size_t)(b*TT + t0)*DD;
        #pragma unroll
        for (int t=0;t<LL;t++){
            float q0 = fmaxf(acc0[t],0.f)*cs[t][j0];
            float q1 = fmaxf(acc1[t],0.f)*cs[t][j1];
            *(float2*)(qcg + t*DD + j0) = make_float2(q0,q1);
        }
    } else if (m==1){ // kh = relu(k)/c ; kb = kh*cL ; Ksum
        float cL0 = cs[LL-1][j0], cL1 = cs[LL-1][j1];
        float ks0=0.f, ks1=0.f;
        float* khg = ws + OFF_KH + (size_t)(b*TT + t0)*DD;
        #pragma unroll
        for (int t=0;t<LL;t++){
            float k0 = fmaxf(acc0[t],0.f);
            float k1 = fmaxf(acc1[t],0.f);
            float kh0 = k0/cs[t][j0];
            float kh1 = k1/cs[t][j1];
            *(float2*)(khg + t*DD + j0) = make_float2(kh0,kh1);
            float kb0 = kh0*cL0, kb1 = kh1*cL1;
            kbs[t][j0]=kb0; kbs[t][j1]=kb1;
            ks0+=kb0; ks1+=kb1;
        }
        float* ksg = ws + OFF_KS + (size_t)bc*DD;
        ksg[j0]=ks0; ksg[j1]=ks1;
    } else if (m==2){ // v
        float* vg = ws + OFF_V + (size_t)(b*TT + t0)*DD;
        #pragma unroll
        for (int t=0;t<LL;t++){
            vsm[t][j0]=acc0[t]; vsm[t][j1]=acc1[t];
            *(float2*)(vg + t*DD + j0) = make_float2(acc0[t],acc1[t]);
        }
    }
    __syncthreads();

    // ---- U[i][j] = sum_u kb[u][i]*v[u][j] ----
    const int j  = tid & 127;
    const int ih = tid >> 7;
    float vr[LL];
    #pragma unroll
    for (int u=0;u<LL;u++) vr[u]=vsm[u][j];
    float* Ug = ws + OFF_U + (size_t)bc*DD*DD;
    #pragma unroll 2
    for (int i4=0;i4<16;i4++){
        int i = ih*64 + i4*4;
        float a0=0.f,a1=0.f,a2=0.f,a3=0.f;
        #pragma unroll
        for (int u=0;u<LL;u++){
            float4 kb4 = *(const float4*)(&kbs[u][i]);
            float vu = vr[u];
            a0 = fmaf(kb4.x,vu,a0); a1 = fmaf(kb4.y,vu,a1);
            a2 = fmaf(kb4.z,vu,a2); a3 = fmaf(kb4.w,vu,a3);
        }
        Ug[(size_t)(i+0)*DD + j]=a0; Ug[(size_t)(i+1)*DD + j]=a1;
        Ug[(size_t)(i+2)*DD + j]=a2; Ug[(size_t)(i+3)*DD + j]=a3;
    }
}

// ---------------------------------------------------------------------------
// Kernel 2: per-element scan over chunks, 8-deep prefetch ring, cL/Ks in LDS.
// block = (b,i), thread = j. Fully parallel, serial dep only on the 4-cy fma.
// ---------------------------------------------------------------------------
__global__ __launch_bounds__(128) void k_scan(float* __restrict__ ws)
{
    __shared__ float cls[CC], kss[CC];
    const int bi = blockIdx.x;      // b*DD + i
    const int b  = bi >> 7;
    const int i  = bi & 127;
    const int j  = threadIdx.x;

    if (j < CC) cls[j]      = ws[OFF_CL + (size_t)(b*CC + j)*DD + i];
    else        kss[j - CC] = ws[OFF_KS + (size_t)(b*CC + j - CC)*DD + i];
    __syncthreads();

    const float* U  = ws + OFF_U;
    float*       s0 = ws + OFF_S0;
    float*       z0 = ws + OFF_Z0;
    const size_t base = (size_t)b*CC*DD*DD + (size_t)i*DD + j;

    float up[8];
    #pragma unroll
    for (int p=0;p<8;p++) up[p] = U[base + (size_t)p*DD*DD];

    float s = 0.f, z = 0.f;
    #pragma unroll
    for (int ch=0; ch<CC; ch++){
        s0[base + (size_t)ch*DD*DD] = s;
        if (j==0) z0[(size_t)(b*CC+ch)*DD + i] = z;
        float u  = up[ch & 7];
        if (ch + 8 < CC) up[ch & 7] = U[base + (size_t)(ch+8)*DD*DD];
        float cl = cls[ch];
        s = fmaf(cl, s, u);
        z = fmaf(cl, z, kss[ch]);
    }
}

// ---------------------------------------------------------------------------
// Kernel 3: per (b,chunk): scores, den, y = (qc@s0 + S@V)/den.
// s0 consumed in 4 slices of 32 rows, register-staged double buffer.
// ---------------------------------------------------------------------------
__global__ __launch_bounds__(256) void k_out(const float* __restrict__ ws, float* __restrict__ y)
{
    __shared__ float qcs[LL][DD+4];
    __shared__ float khs[LL][DD+4];
    __shared__ float vsm[LL][DD+4];
    __shared__ float Ss[LL][LL];
    __shared__ float denS[LL];
    __shared__ float z0s[DD];
    __shared__ float s0s[2][32][DD];

    const int tid = threadIdx.x;
    const int bc  = blockIdx.x;
    const int b   = bc / CC;
    const int ch  = bc % CC;
    const int t0  = ch * LL;
    const float* s0g = ws + OFF_S0 + (size_t)bc*DD*DD;

    // coop load qc/kh/v tiles + z0, and issue slice-0 prefetch of s0
    float4 pre[4];
    {
        const float4* qcg = (const float4*)(ws + OFF_QC + (size_t)(b*TT+t0)*DD);
        const float4* khg = (const float4*)(ws + OFF_KH + (size_t)(b*TT+t0)*DD);
        const float4* vg  = (const float4*)(ws + OFF_V  + (size_t)(b*TT+t0)*DD);
        #pragma unroll
        for (int rep=0; rep<2; rep++){
            int f = tid + rep*256;
            int t = f >> 5, k4 = f & 31;
            *(float4*)&qcs[t][k4*4] = qcg[f];
            *(float4*)&khs[t][k4*4] = khg[f];
            *(float4*)&vsm[t][k4*4] = vg [f];
        }
        if (tid < DD) z0s[tid] = ws[OFF_Z0 + (size_t)bc*DD + tid];
        const float4* sg = (const float4*)s0g;
        #pragma unroll
        for (int r=0;r<4;r++) pre[r] = sg[tid + r*256];   // slice 0 (32 rows)
    }
    __syncthreads();

    // scores S[t][u] = qc_t . kh_u, masked u<=t
    {
        int t = tid >> 4, u = tid & 15;
        float s = 0.f;
        #pragma unroll 8
        for (int k4=0; k4<32; k4++){
            float4 q4 = *(const float4*)&qcs[t][k4*4];
            float4 h4 = *(const float4*)&khs[u][k4*4];
            s = fmaf(q4.x,h4.x, fmaf(q4.y,h4.y, fmaf(q4.z,h4.z, fmaf(q4.w,h4.w, s))));
        }
        Ss[t][u] = (u <= t) ? s : 0.f;
    }
    __syncthreads();

    if (tid < LL){
        int t = tid;
        float d = EPSV;
        for (int u=0; u<=t; u++) d += Ss[t][u];
        #pragma unroll 8
        for (int kk=0; kk<DD; kk++) d += qcs[t][kk]*z0s[kk];
        denS[t] = d;
    }

    const int t  = tid >> 4;
    const int jg = tid & 15;
    const int j0 = jg * 8;
    float y8[8];
    #pragma unroll
    for (int jj=0;jj<8;jj++) y8[jj]=0.f;

    // intra-chunk: S @ V
    __syncthreads();
    #pragma unroll
    for (int u=0; u<LL; u++){
        float sv = Ss[t][u];
        float4 v4a = *(const float4*)&vsm[u][j0];
        float4 v4b = *(const float4*)&vsm[u][j0+4];
        y8[0]=fmaf(sv,v4a.x,y8[0]); y8[1]=fmaf(sv,v4a.y,y8[1]);
        y8[2]=fmaf(sv,v4a.z,y8[2]); y8[3]=fmaf(sv,v4a.w,y8[3]);
        y8[4]=fmaf(sv,v4b.x,y8[4]); y8[5]=fmaf(sv,v4b.y,y8[5]);
        y8[6]=fmaf(sv,v4b.z,y8[6]); y8[7]=fmaf(sv,v4b.w,y8[7]);
    }

    // inter-chunk: qc @ s0, 4 slices of 32 rows, double-buffered
    #pragma unroll
    for (int sl=0; sl<4; sl++){
        __syncthreads();                     // buf[sl&1] free
        {
            float* dstb = &s0s[sl&1][0][0];
            #pragma unroll
            for (int r=0;r<4;r++) *(float4*)(dstb + (tid + r*256)*4) = pre[r];
        }
        if (sl < 3){
            const float4* sg = (const float4*)(s0g + (size_t)(sl+1)*32*DD);
            #pragma unroll
            for (int r=0;r<4;r++) pre[r] = sg[tid + r*256];
        }
        __syncthreads();
        #pragma unroll 8
        for (int ii=0; ii<32; ii++){
            float qv = qcs[t][sl*32+ii];
            float4 s4a = *(const float4*)&s0s[sl&1][ii][j0];
            float4 s4b = *(const float4*)&s0s[sl&1][ii][j0+4];
            y8[0]=fmaf(qv,s4a.x,y8[0]); y8[1]=fmaf(qv,s4a.y,y8[1]);
            y8[2]=fmaf(qv,s4a.z,y8[2]); y8[3]=fmaf(qv,s4a.w,y8[3]);
            y8[4]=fmaf(qv,s4b.x,y8[4]); y8[5]=fmaf(qv,s4b.y,y8[5]);
            y8[6]=fmaf(qv,s4b.z,y8[6]); y8[7]=fmaf(qv,s4b.w,y8[7]);
        }
    }

    const float rd = 1.f/denS[t];
    float* yg = y + (size_t)(b*TT + t0 + t)*DD + j0;
    float4 o0 = make_float4(y8[0]*rd, y8[1]*rd, y8[2]*rd, y8[3]*rd);
    float4 o1 = make_float4(y8[4]*rd, y8[5]*rd, y8[6]*rd, y8[7]*rd);
    *(float4*)(yg)     = o0;
    *(float4*)(yg + 4) = o1;
}

extern "C" void kernel_launch(void* const* d_in, const int* in_sizes, int n_in,
                              void* d_out, int out_size, void* d_ws, size_t ws_size,
                              hipStream_t stream)
{
    const float* x  = (const float*)d_in[0];
    const float* Wq = (const float*)d_in[1]; const float* bq = (const float*)d_in[2];
    const float* Wk = (const float*)d_in[3]; const float* bk = (const float*)d_in[4];
    const float* Wv = (const float*)d_in[5]; const float* bv = (const float*)d_in[6];
    const float* Wa = (const float*)d_in[7]; const float* ba = (const float*)d_in[8];
    float* ws = (float*)d_ws;
    float* wt = ws + OFF_WT;
    float* yo = (float*)d_out;

    hipLaunchKernelGGL(k_tw,   dim3(8),     dim3(256), 0, stream, Wq, Wk, Wv, Wa, wt);
    hipLaunchKernelGGL(k_proj, dim3(BB*CC), dim3(256), 0, stream, x, bq, bk, bv, ba, wt, ws);
    hipLaunchKernelGGL(k_scan, dim3(BB*DD), dim3(128), 0, stream, ws);
    hipLaunchKernelGGL(k_out,  dim3(BB*CC), dim3(256), 0, stream, ws, yo);
}

// Round 4
// 146.281 us; speedup vs baseline: 1.0131x; 1.0131x over previous
//
#include <hip/hip_runtime.h>

#define BB 4
#define TT 1024
#define DD 128
#define LL 16
#define CC 64   // TT/LL
#define EPSV 1e-6f

// workspace offsets (floats)
#define OFF_QC   0
#define OFF_KH   (OFF_QC + BB*TT*DD)
#define OFF_V    (OFF_KH + BB*TT*DD)
#define OFF_CL   (OFF_V  + BB*TT*DD)
#define OFF_KS   (OFF_CL + BB*CC*DD)
#define OFF_Z0   (OFF_KS + BB*CC*DD)
#define OFF_U    (OFF_Z0 + BB*CC*DD)
#define OFF_S0   (OFF_U  + BB*CC*DD*DD)
#define OFF_G    (OFF_S0 + BB*CC*DD*DD)
// total ~= 44 MB floats (ws is 256 MiB)

// ---------------------------------------------------------------------------
// Kernel 1: fused 4-projection GEMM. M=4096 rows, N=4 mats x 128 cols, K=128.
// Tile: BM=32 rows x BN=64 cols (half a matrix). grid = 128 row-tiles x 8
// (mat,half) = 1024 blocks -> 3 blocks/CU (LDS-capped) = 12 waves/CU.
// Thread: 2 rows x 4 cols = 8 accumulators, 1024 fma.
// Activations fused: relu(q), relu(k), v, sigmoid(a)->g.
// ---------------------------------------------------------------------------
__global__ __launch_bounds__(256) void k_gemm(
    const float* __restrict__ x,
    const float* __restrict__ Wq, const float* __restrict__ bq,
    const float* __restrict__ Wk, const float* __restrict__ bk,
    const float* __restrict__ Wv, const float* __restrict__ bv,
    const float* __restrict__ Wa, const float* __restrict__ ba,
    float* __restrict__ ws)
{
    __shared__ float xs [32][DD];      // 16 KB, reads are wave-broadcast
    __shared__ float wsh[64][132];     // 33.8 KB, pad->2-way (free) col reads

    const int tid = threadIdx.x;
    const int bx  = blockIdx.x;
    const int rt  = bx >> 3;           // row-tile 0..127
    const int mt  = bx & 7;
    const int m   = mt >> 1;           // matrix 0:q 1:k 2:v 3:a
    const int jh  = mt & 1;            // column half

    const float* W    = (m==0)?Wq : (m==1)?Wk : (m==2)?Wv : Wa;
    const float* bias = (m==0)?bq : (m==1)?bk : (m==2)?bv : ba;

    // stage x tile (32x128) and W half (64x128)
    {
        const float4* xg = (const float4*)(x + (size_t)rt*32*DD);
        #pragma unroll
        for (int r=0;r<4;r++){
            int f = tid + r*256;       // 1024 f4
            *(float4*)&xs[f>>5][(f&31)*4] = xg[f];
        }
        const float4* wg = (const float4*)(W + (size_t)jh*64*DD);
        #pragma unroll
        for (int r=0;r<8;r++){
            int f = tid + r*256;       // 2048 f4
            *(float4*)&wsh[f>>5][(f&31)*4] = wg[f];
        }
    }
    __syncthreads();

    const int ci = tid & 15;           // strided col owner: cols ci+16*cc
    const int ri = tid >> 4;           // rows ri, ri+16

    float acc[2][4];
    #pragma unroll
    for (int cc=0;cc<4;cc++){
        float bv_ = bias[jh*64 + ci + 16*cc];
        acc[0][cc]=bv_; acc[1][cc]=bv_;
    }

    #pragma unroll 2
    for (int k4=0; k4<32; k4++){
        float4 xa = *(const float4*)&xs[ri   ][k4*4];
        float4 xb = *(const float4*)&xs[ri+16][k4*4];
        #pragma unroll
        for (int cc=0;cc<4;cc++){
            float4 w = *(const float4*)&wsh[ci+16*cc][k4*4];
            acc[0][cc] = fmaf(xa.x,w.x, fmaf(xa.y,w.y, fmaf(xa.z,w.z, fmaf(xa.w,w.w, acc[0][cc]))));
            acc[1][cc] = fmaf(xb.x,w.x, fmaf(xb.y,w.y, fmaf(xb.z,w.z, fmaf(xb.w,w.w, acc[1][cc]))));
        }
    }

    float* dst = ws + ((m==0)?OFF_QC : (m==1)?OFF_KH : (m==2)?OFF_V : OFF_G);
    #pragma unroll
    for (int rr=0;rr<2;rr++){
        int row = rt*32 + ri + 16*rr;
        #pragma unroll
        for (int cc=0;cc<4;cc++){
            float v = acc[rr][cc];
            if (m==0 || m==1) v = fmaxf(v, 0.f);
            else if (m==3)    v = 1.f/(1.f+__expf(-v));
            dst[(size_t)row*DD + jh*64 + ci + 16*cc] = v;
        }
    }
}

// ---------------------------------------------------------------------------
// Kernel 2: per (b,chunk) postprocess. Reads staged qr,kr,v,g tiles; computes
// in-chunk cumprod c, writes qc=qr*c (over QC), kh=kr/c (over KH), cL, Ksum,
// and U = kb^T V (kb = kh*cL).
// ---------------------------------------------------------------------------
__global__ __launch_bounds__(256) void k_chunk(float* __restrict__ ws)
{
    __shared__ float qs [LL][DD];
    __shared__ float ksm[LL][DD];
    __shared__ float vs [LL][DD];
    __shared__ float gs [LL][DD];   // becomes cumprod c in place
    __shared__ float kbs[LL][DD];

    const int tid = threadIdx.x;
    const int bc  = blockIdx.x;        // b*CC + ch
    const int b   = bc / CC;
    const int t0  = (bc % CC) * LL;
    const size_t tile = (size_t)(b*TT + t0)*DD;

    // stage 4 tiles (each 512 f4)
    {
        const float4* qg = (const float4*)(ws + OFF_QC + tile);
        const float4* kg = (const float4*)(ws + OFF_KH + tile);
        const float4* vg = (const float4*)(ws + OFF_V  + tile);
        const float4* gg = (const float4*)(ws + OFF_G  + tile);
        #pragma unroll
        for (int r=0;r<2;r++){
            int f = tid + r*256;
            int t = f >> 5, c4 = (f & 31)*4;
            *(float4*)&qs [t][c4] = qg[f];
            *(float4*)&ksm[t][c4] = kg[f];
            *(float4*)&vs [t][c4] = vg[f];
            *(float4*)&gs [t][c4] = gg[f];
        }
    }
    __syncthreads();

    // cumprod per column (threads 0..127)
    if (tid < DD){
        float c = 1.f;
        #pragma unroll
        for (int t=0;t<LL;t++){ c *= gs[t][tid]; gs[t][tid] = c; }
        ws[OFF_CL + (size_t)bc*DD + tid] = c;
    }
    __syncthreads();

    if (tid < DD){                     // waves 0-1: kh, kb, Ksum
        const int j = tid;
        const float cl = gs[LL-1][j];
        float ksum = 0.f;
        float* khg = ws + OFF_KH + tile;
        #pragma unroll
        for (int t=0;t<LL;t++){
            float kh = ksm[t][j] / gs[t][j];
            khg[t*DD + j] = kh;
            float kb = kh * cl;
            kbs[t][j] = kb;
            ksum += kb;
        }
        ws[OFF_KS + (size_t)bc*DD + j] = ksum;
    } else {                           // waves 2-3: qc
        const int j = tid - DD;
        float* qcg = ws + OFF_QC + tile;
        #pragma unroll
        for (int t=0;t<LL;t++)
            qcg[t*DD + j] = qs[t][j] * gs[t][j];
    }
    __syncthreads();

    // U[i][j] = sum_u kb[u][i]*v[u][j]
    const int j  = tid & 127;
    const int ih = tid >> 7;
    float vr[LL];
    #pragma unroll
    for (int u=0;u<LL;u++) vr[u]=vs[u][j];
    float* Ug = ws + OFF_U + (size_t)bc*DD*DD;
    #pragma unroll 2
    for (int i4=0;i4<16;i4++){
        int i = ih*64 + i4*4;
        float a0=0.f,a1=0.f,a2=0.f,a3=0.f;
        #pragma unroll
        for (int u=0;u<LL;u++){
            float4 kb4 = *(const float4*)(&kbs[u][i]);   // broadcast read
            float vu = vr[u];
            a0 = fmaf(kb4.x,vu,a0); a1 = fmaf(kb4.y,vu,a1);
            a2 = fmaf(kb4.z,vu,a2); a3 = fmaf(kb4.w,vu,a3);
        }
        Ug[(size_t)(i+0)*DD + j]=a0; Ug[(size_t)(i+1)*DD + j]=a1;
        Ug[(size_t)(i+2)*DD + j]=a2; Ug[(size_t)(i+3)*DD + j]=a3;
    }
}

// ---------------------------------------------------------------------------
// Kernel 3: per-element scan over chunks, 8-deep prefetch ring, cL/Ks in LDS.
// ---------------------------------------------------------------------------
__global__ __launch_bounds__(128) void k_scan(float* __restrict__ ws)
{
    __shared__ float cls[CC], kss[CC];
    const int bi = blockIdx.x;      // b*DD + i
    const int b  = bi >> 7;
    const int i  = bi & 127;
    const int j  = threadIdx.x;

    if (j < CC) cls[j]      = ws[OFF_CL + (size_t)(b*CC + j)*DD + i];
    else        kss[j - CC] = ws[OFF_KS + (size_t)(b*CC + j - CC)*DD + i];
    __syncthreads();

    const float* U  = ws + OFF_U;
    float*       s0 = ws + OFF_S0;
    float*       z0 = ws + OFF_Z0;
    const size_t base = (size_t)b*CC*DD*DD + (size_t)i*DD + j;

    float up[8];
    #pragma unroll
    for (int p=0;p<8;p++) up[p] = U[base + (size_t)p*DD*DD];

    float s = 0.f, z = 0.f;
    #pragma unroll
    for (int ch=0; ch<CC; ch++){
        s0[base + (size_t)ch*DD*DD] = s;
        if (j==0) z0[(size_t)(b*CC+ch)*DD + i] = z;
        float u  = up[ch & 7];
        if (ch + 8 < CC) up[ch & 7] = U[base + (size_t)(ch+8)*DD*DD];
        float cl = cls[ch];
        s = fmaf(cl, s, u);
        z = fmaf(cl, z, kss[ch]);
    }
}

// ---------------------------------------------------------------------------
// Kernel 4: per (b,chunk): scores, den, y = (qc@s0 + S@V)/den.
// ---------------------------------------------------------------------------
__global__ __launch_bounds__(256) void k_out(const float* __restrict__ ws, float* __restrict__ y)
{
    __shared__ float qcs[LL][DD+4];
    __shared__ float khs[LL][DD+4];
    __shared__ float vsm[LL][DD+4];
    __shared__ float Ss[LL][LL];
    __shared__ float denS[LL];
    __shared__ float z0s[DD];
    __shared__ float s0s[2][32][DD];

    const int tid = threadIdx.x;
    const int bc  = blockIdx.x;
    const int b   = bc / CC;
    const int ch  = bc % CC;
    const int t0  = ch * LL;
    const float* s0g = ws + OFF_S0 + (size_t)bc*DD*DD;

    float4 pre[4];
    {
        const float4* qcg = (const float4*)(ws + OFF_QC + (size_t)(b*TT+t0)*DD);
        const float4* khg = (const float4*)(ws + OFF_KH + (size_t)(b*TT+t0)*DD);
        const float4* vg  = (const float4*)(ws + OFF_V  + (size_t)(b*TT+t0)*DD);
        #pragma unroll
        for (int rep=0; rep<2; rep++){
            int f = tid + rep*256;
            int t = f >> 5, k4 = f & 31;
            *(float4*)&qcs[t][k4*4] = qcg[f];
            *(float4*)&khs[t][k4*4] = khg[f];
            *(float4*)&vsm[t][k4*4] = vg [f];
        }
        if (tid < DD) z0s[tid] = ws[OFF_Z0 + (size_t)bc*DD + tid];
        const float4* sg = (const float4*)s0g;
        #pragma unroll
        for (int r=0;r<4;r++) pre[r] = sg[tid + r*256];   // slice 0 (32 rows)
    }
    __syncthreads();

    {
        int t = tid >> 4, u = tid & 15;
        float s = 0.f;
        #pragma unroll 8
        for (int k4=0; k4<32; k4++){
            float4 q4 = *(const float4*)&qcs[t][k4*4];
            float4 h4 = *(const float4*)&khs[u][k4*4];
            s = fmaf(q4.x,h4.x, fmaf(q4.y,h4.y, fmaf(q4.z,h4.z, fmaf(q4.w,h4.w, s))));
        }
        Ss[t][u] = (u <= t) ? s : 0.f;
    }
    __syncthreads();

    if (tid < LL){
        int t = tid;
        float d = EPSV;
        for (int u=0; u<=t; u++) d += Ss[t][u];
        #pragma unroll 8
        for (int kk=0; kk<DD; kk++) d += qcs[t][kk]*z0s[kk];
        denS[t] = d;
    }

    const int t  = tid >> 4;
    const int jg = tid & 15;
    const int j0 = jg * 8;
    float y8[8];
    #pragma unroll
    for (int jj=0;jj<8;jj++) y8[jj]=0.f;

    __syncthreads();
    #pragma unroll
    for (int u=0; u<LL; u++){
        float sv = Ss[t][u];
        float4 v4a = *(const float4*)&vsm[u][j0];
        float4 v4b = *(const float4*)&vsm[u][j0+4];
        y8[0]=fmaf(sv,v4a.x,y8[0]); y8[1]=fmaf(sv,v4a.y,y8[1]);
        y8[2]=fmaf(sv,v4a.z,y8[2]); y8[3]=fmaf(sv,v4a.w,y8[3]);
        y8[4]=fmaf(sv,v4b.x,y8[4]); y8[5]=fmaf(sv,v4b.y,y8[5]);
        y8[6]=fmaf(sv,v4b.z,y8[6]); y8[7]=fmaf(sv,v4b.w,y8[7]);
    }

    #pragma unroll
    for (int sl=0; sl<4; sl++){
        __syncthreads();
        {
            float* dstb = &s0s[sl&1][0][0];
            #pragma unroll
            for (int r=0;r<4;r++) *(float4*)(dstb + (tid + r*256)*4) = pre[r];
        }
        if (sl < 3){
            const float4* sg = (const float4*)(s0g + (size_t)(sl+1)*32*DD);
            #pragma unroll
            for (int r=0;r<4;r++) pre[r] = sg[tid + r*256];
        }
        __syncthreads();
        #pragma unroll 8
        for (int ii=0; ii<32; ii++){
            float qv = qcs[t][sl*32+ii];
            float4 s4a = *(const float4*)&s0s[sl&1][ii][j0];
            float4 s4b = *(const float4*)&s0s[sl&1][ii][j0+4];
            y8[0]=fmaf(qv,s4a.x,y8[0]); y8[1]=fmaf(qv,s4a.y,y8[1]);
            y8[2]=fmaf(qv,s4a.z,y8[2]); y8[3]=fmaf(qv,s4a.w,y8[3]);
            y8[4]=fmaf(qv,s4b.x,y8[4]); y8[5]=fmaf(qv,s4b.y,y8[5]);
            y8[6]=fmaf(qv,s4b.z,y8[6]); y8[7]=fmaf(qv,s4b.w,y8[7]);
        }
    }

    const float rd = 1.f/denS[t];
    float* yg = y + (size_t)(b*TT + t0 + t)*DD + j0;
    float4 o0 = make_float4(y8[0]*rd, y8[1]*rd, y8[2]*rd, y8[3]*rd);
    float4 o1 = make_float4(y8[4]*rd, y8[5]*rd, y8[6]*rd, y8[7]*rd);
    *(float4*)(yg)     = o0;
    *(float4*)(yg + 4) = o1;
}

extern "C" void kernel_launch(void* const* d_in, const int* in_sizes, int n_in,
                              void* d_out, int out_size, void* d_ws, size_t ws_size,
                              hipStream_t stream)
{
    const float* x  = (const float*)d_in[0];
    const float* Wq = (const float*)d_in[1]; const float* bq = (const float*)d_in[2];
    const float* Wk = (const float*)d_in[3]; const float* bk = (const float*)d_in[4];
    const float* Wv = (const float*)d_in[5]; const float* bv = (const float*)d_in[6];
    const float* Wa = (const float*)d_in[7]; const float* ba = (const float*)d_in[8];
    float* ws = (float*)d_ws;
    float* yo = (float*)d_out;

    hipLaunchKernelGGL(k_gemm,  dim3(1024),  dim3(256), 0, stream,
                       x, Wq,bq, Wk,bk, Wv,bv, Wa,ba, ws);
    hipLaunchKernelGGL(k_chunk, dim3(BB*CC), dim3(256), 0, stream, ws);
    hipLaunchKernelGGL(k_scan,  dim3(BB*DD), dim3(128), 0, stream, ws);
    hipLaunchKernelGGL(k_out,   dim3(BB*CC), dim3(256), 0, stream, ws, yo);
}